// Round 6
// baseline (398.629 us; speedup 1.0000x reference)
//
#include <hip/hip_runtime.h>

#define M_DIM 32
#define K_DIM 4096
#define N_DIM 16384
#define BN 16          // weight rows per block
#define BK 256         // k (ints) per stage -> 1 KB contiguous per row per stage
#define NST 16         // K_DIM / BK
#define LROW 264       // ushorts per LDS row: 256 + 8 pad

using short8 = __attribute__((ext_vector_type(8))) short;
using f32x4  = __attribute__((ext_vector_type(4))) float;

// Barrier waiting only LDS ops (lgkmcnt) — keeps global prefetch in flight.
#define LDS_BARRIER() asm volatile("s_waitcnt lgkmcnt(0)\n\ts_barrier" ::: "memory")

__device__ __forceinline__ ushort f2bf_rne(float f) {
    unsigned u = __float_as_uint(f);
    u += 0x7fffu + ((u >> 16) & 1u);
    return (ushort)(u >> 16);
}

// Exact for integers |v| <= 256 (fits in 8 significand bits -> truncation lossless)
__device__ __forceinline__ ushort i2bf_exact(int v) {
    return (ushort)(__float_as_uint((float)v) >> 16);
}

__device__ __forceinline__ ushort4 cvt4(int4 v, int zero) {
    ushort4 o;
    o.x = i2bf_exact(v.x - zero);
    o.y = i2bf_exact(v.y - zero);
    o.z = i2bf_exact(v.z - zero);
    o.w = i2bf_exact(v.w - zero);
    return o;
}

__global__ __launch_bounds__(256) void prep_x_kernel(const float* __restrict__ x,
                                                     ushort* __restrict__ xb) {
    int i = blockIdx.x * blockDim.x + threadIdx.x;   // 32768 threads x 4 elems
    float4 v = reinterpret_cast<const float4*>(x)[i];
    ushort4 o;
    o.x = f2bf_rne(v.x); o.y = f2bf_rne(v.y); o.z = f2bf_rne(v.z); o.w = f2bf_rne(v.w);
    reinterpret_cast<ushort4*>(xb)[i] = o;
}

__global__ __launch_bounds__(256) void qgemm_kernel(
        const ushort* __restrict__ xb, const int* __restrict__ wq,
        const int* __restrict__ zerop, const float* __restrict__ scalep,
        const float* __restrict__ bias, float* __restrict__ out) {
    __shared__ ushort tile[BN][LROW];        // 8448 B, single stage buffer
    __shared__ float  red[4][M_DIM][BN];     // 8 KB, split-K reduction

    const int tid  = threadIdx.x;
    const int wave = tid >> 6;
    const int lane = tid & 63;
    const int quad = lane >> 4;
    const int l16  = lane & 15;
    const int n0   = blockIdx.x * BN;
    const int zero = *zerop;
    const int phase = blockIdx.x & (NST - 1);   // decorrelate k-phase across blocks

    // B staging: wave w owns rows 4w..4w+3; ONE dwordx4 wave-instruction per row
    // = 64 lanes x 16 B = 1 KB fully contiguous.
    const int r0 = wave << 2;
    const int* gR0 = wq + (size_t)(n0 + r0 + 0) * K_DIM + (lane << 2);
    const int* gR1 = wq + (size_t)(n0 + r0 + 1) * K_DIM + (lane << 2);
    const int* gR2 = wq + (size_t)(n0 + r0 + 2) * K_DIM + (lane << 2);
    const int* gR3 = wq + (size_t)(n0 + r0 + 3) * K_DIM + (lane << 2);

    // A-fragments: m = l16 (+16), k = stage*256 + wave*64 + sub*32 + quad*8
    const ushort* axp0 = xb + (size_t)l16 * K_DIM + (wave << 6) + (quad << 3);
    const ushort* axp1 = axp0 + 16 * K_DIM;

    f32x4 acc0 = {0.f, 0.f, 0.f, 0.f};
    f32x4 acc1 = {0.f, 0.f, 0.f, 0.f};

    // ---- prologue: 2-stage B prefetch, 1-stage A prefetch ----
    const int k0p = phase * BK;
    const int k1p = ((phase + 1) & (NST - 1)) * BK;
    int4 c0 = *(const int4*)(gR0 + k0p), c1 = *(const int4*)(gR1 + k0p);
    int4 c2 = *(const int4*)(gR2 + k0p), c3 = *(const int4*)(gR3 + k0p);
    int4 d0 = *(const int4*)(gR0 + k1p), d1 = *(const int4*)(gR1 + k1p);
    int4 d2 = *(const int4*)(gR2 + k1p), d3 = *(const int4*)(gR3 + k1p);
    short8 aA0 = *(const short8*)(axp0 + k0p);        // sub0, M-tile 0
    short8 aA1 = *(const short8*)(axp0 + k0p + 32);   // sub1, M-tile 0
    short8 aA2 = *(const short8*)(axp1 + k0p);        // sub0, M-tile 1
    short8 aA3 = *(const short8*)(axp1 + k0p + 32);   // sub1, M-tile 1

    #pragma unroll 2
    for (int s = 0; s < NST; ++s) {
        int4 nb0, nb1, nb2, nb3;
        if (s + 2 < NST) {                        // B for stage s+2 (2 ahead)
            int kn = ((s + 2 + phase) & (NST - 1)) * BK;
            nb0 = *(const int4*)(gR0 + kn); nb1 = *(const int4*)(gR1 + kn);
            nb2 = *(const int4*)(gR2 + kn); nb3 = *(const int4*)(gR3 + kn);
        }
        short8 na0, na1, na2, na3;
        if (s + 1 < NST) {                        // A for stage s+1 (L2-resident)
            int ka = ((s + 1 + phase) & (NST - 1)) * BK;
            na0 = *(const short8*)(axp0 + ka);
            na1 = *(const short8*)(axp0 + ka + 32);
            na2 = *(const short8*)(axp1 + ka);
            na3 = *(const short8*)(axp1 + ka + 32);
        }

        LDS_BARRIER();                            // WAR: all waves done reading tile
        *(ushort4*)&tile[r0 + 0][lane << 2] = cvt4(c0, zero);
        *(ushort4*)&tile[r0 + 1][lane << 2] = cvt4(c1, zero);
        *(ushort4*)&tile[r0 + 2][lane << 2] = cvt4(c2, zero);
        *(ushort4*)&tile[r0 + 3][lane << 2] = cvt4(c3, zero);
        LDS_BARRIER();                            // RAW: tile writes visible

        const ushort* rp = &tile[l16][(wave << 6) + (quad << 3)];
        short8 bf0 = *(const short8*)(rp);        // sub0 (k +0..31)
        short8 bf1 = *(const short8*)(rp + 32);   // sub1 (k +32..63)
        acc0 = __builtin_amdgcn_mfma_f32_16x16x32_bf16(aA0, bf0, acc0, 0, 0, 0);
        acc1 = __builtin_amdgcn_mfma_f32_16x16x32_bf16(aA2, bf0, acc1, 0, 0, 0);
        acc0 = __builtin_amdgcn_mfma_f32_16x16x32_bf16(aA1, bf1, acc0, 0, 0, 0);
        acc1 = __builtin_amdgcn_mfma_f32_16x16x32_bf16(aA3, bf1, acc1, 0, 0, 0);

        c0 = d0; c1 = d1; c2 = d2; c3 = d3;       // rotate prefetch pipeline
        d0 = nb0; d1 = nb1; d2 = nb2; d3 = nb3;
        aA0 = na0; aA1 = na1; aA2 = na2; aA3 = na3;
    }

    // ---- split-K reduction (v1-verified layout: C row = quad*4+i, col = l16) ----
    __syncthreads();
    #pragma unroll
    for (int i = 0; i < 4; ++i) {
        red[wave][(quad << 2) + i][l16]      = acc0[i];
        red[wave][16 + (quad << 2) + i][l16] = acc1[i];
    }
    __syncthreads();

    const float scale = *scalep;
    #pragma unroll
    for (int t = 0; t < 2; ++t) {
        int idx = tid + (t << 8);                 // 512 outputs, 256 threads
        int row = idx >> 4;
        int c   = idx & 15;
        float s = red[0][row][c] + red[1][row][c] + red[2][row][c] + red[3][row][c];
        out[(size_t)row * N_DIM + n0 + c] = fmaf(scale, s, bias[n0 + c]);
    }
}

extern "C" void kernel_launch(void* const* d_in, const int* in_sizes, int n_in,
                              void* d_out, int out_size, void* d_ws, size_t ws_size,
                              hipStream_t stream) {
    const float* x      = (const float*)d_in[0];
    const int*   wq     = (const int*)d_in[1];
    const int*   zerop  = (const int*)d_in[2];
    const float* scalep = (const float*)d_in[3];
    const float* bias   = (const float*)d_in[4];
    float*       out    = (float*)d_out;
    ushort*      xb     = (ushort*)d_ws;   // 32*4096 bf16 = 256 KB scratch

    prep_x_kernel<<<(M_DIM * K_DIM / 4) / 256, 256, 0, stream>>>(x, xb);
    qgemm_kernel<<<N_DIM / BN, 256, 0, stream>>>(xb, wq, zerop, scalep, bias, out);
}

// Round 7
// 383.910 us; speedup vs baseline: 1.0383x; 1.0383x over previous
//
#include <hip/hip_runtime.h>

#define M_DIM 32
#define K_DIM 4096
#define N_DIM 16384
#define KQ 1024        // k per block (quarter)
#define LP 1032        // ushorts per LDS tile row (1024 + 8 pad)

using short8 = __attribute__((ext_vector_type(8))) short;
using f32x4  = __attribute__((ext_vector_type(4))) float;

__device__ __forceinline__ ushort f2bf_rne(float f) {
    unsigned u = __float_as_uint(f);
    u += 0x7fffu + ((u >> 16) & 1u);
    return (ushort)(u >> 16);
}

// Exact for integers |v| <= 256 (fits in 8 significand bits -> truncation lossless)
__device__ __forceinline__ ushort i2bf_exact(int v) {
    return (ushort)(__float_as_uint((float)v) >> 16);
}

__device__ __forceinline__ ushort4 cvt4(int4 v, int zero) {
    ushort4 o;
    o.x = i2bf_exact(v.x - zero);
    o.y = i2bf_exact(v.y - zero);
    o.z = i2bf_exact(v.z - zero);
    o.w = i2bf_exact(v.w - zero);
    return o;
}

// Block (nt, kq): rows nt*16..+16, k in [kq*1024, +1024). Whole 64 KB W-tile is
// loaded into LDS ONCE (rows as 4 KB sequential runs; kq fastest block index ->
// concurrent blocks sweep W as a dense contiguous window). One barrier total.
__global__ __launch_bounds__(256) void qgemm_part_kernel(
        const float* __restrict__ x, const int* __restrict__ wq,
        const int* __restrict__ zerop, float* __restrict__ partial) {
    __shared__ ushort tile[16][LP];          // 33,024 B
    __shared__ float  red[4][M_DIM][16];     // 8,192 B

    const int tid  = threadIdx.x;
    const int wave = tid >> 6;
    const int lane = tid & 63;
    const int quad = lane >> 4;
    const int l16  = lane & 15;
    const int kq   = blockIdx.x & 3;         // fastest: k-quarter
    const int nt   = blockIdx.x >> 2;
    const int n0   = nt << 4;
    const int kbase = kq << 10;
    const int zero = *zerop;

    // ---- load the whole 16x1024 W-tile (64 KB) into LDS, rows sequential ----
    const int* gW = wq + (size_t)n0 * K_DIM + kbase;
    #pragma unroll
    for (int i = 0; i < 16; ++i) {           // iteration i = row i; 4 KB run
        int4 v = *(const int4*)(gW + ((size_t)i << 12) + (tid << 2));
        *(ushort4*)&tile[i][tid << 2] = cvt4(v, zero);
    }
    __syncthreads();

    // ---- compute: wave w covers klocal in [w*256, +256) = 8 k-steps ----
    f32x4 acc0 = {0.f, 0.f, 0.f, 0.f};
    f32x4 acc1 = {0.f, 0.f, 0.f, 0.f};
    const int kl0 = wave << 8;
    const float* ax0 = x + (size_t)l16 * K_DIM + kbase + kl0 + (quad << 3);
    const float* ax1 = ax0 + 16 * K_DIM;

    #pragma unroll
    for (int s = 0; s < 8; ++s) {
        const int ko = s << 5;
        float4 lo0 = *(const float4*)(ax0 + ko);
        float4 hi0 = *(const float4*)(ax0 + ko + 4);
        float4 lo1 = *(const float4*)(ax1 + ko);
        float4 hi1 = *(const float4*)(ax1 + ko + 4);
        short8 a0, a1;
        a0[0] = (short)f2bf_rne(lo0.x); a0[1] = (short)f2bf_rne(lo0.y);
        a0[2] = (short)f2bf_rne(lo0.z); a0[3] = (short)f2bf_rne(lo0.w);
        a0[4] = (short)f2bf_rne(hi0.x); a0[5] = (short)f2bf_rne(hi0.y);
        a0[6] = (short)f2bf_rne(hi0.z); a0[7] = (short)f2bf_rne(hi0.w);
        a1[0] = (short)f2bf_rne(lo1.x); a1[1] = (short)f2bf_rne(lo1.y);
        a1[2] = (short)f2bf_rne(lo1.z); a1[3] = (short)f2bf_rne(lo1.w);
        a1[4] = (short)f2bf_rne(hi1.x); a1[5] = (short)f2bf_rne(hi1.y);
        a1[6] = (short)f2bf_rne(hi1.z); a1[7] = (short)f2bf_rne(hi1.w);
        short8 bf = *(const short8*)&tile[l16][kl0 + ko + (quad << 3)];
        acc0 = __builtin_amdgcn_mfma_f32_16x16x32_bf16(a0, bf, acc0, 0, 0, 0);
        acc1 = __builtin_amdgcn_mfma_f32_16x16x32_bf16(a1, bf, acc1, 0, 0, 0);
    }

    // ---- in-block split-K reduce (C layout verified: row=quad*4+i, col=l16) ----
    #pragma unroll
    for (int i = 0; i < 4; ++i) {
        red[wave][(quad << 2) + i][l16]      = acc0[i];
        red[wave][16 + (quad << 2) + i][l16] = acc1[i];
    }
    __syncthreads();

    #pragma unroll
    for (int t = 0; t < 2; ++t) {
        int idx = tid + (t << 8);            // 512 outputs
        int row = idx >> 4;
        int col = idx & 15;
        float s = red[0][row][col] + red[1][row][col]
                + red[2][row][col] + red[3][row][col];
        partial[(size_t)(kq * M_DIM + row) * N_DIM + n0 + col] = s;
    }
}

// Deterministic cross-quarter reduction + scale/bias epilogue.
__global__ __launch_bounds__(256) void reduce_kernel(
        const float* __restrict__ partial, const float* __restrict__ scalep,
        const float* __restrict__ bias, float* __restrict__ out) {
    const int j = blockIdx.x * 256 + threadIdx.x;   // float4 index, 131072 total
    const float4* p = (const float4*)partial;
    float4 p0 = p[j], p1 = p[j + 131072], p2 = p[j + 262144], p3 = p[j + 393216];
    const float sc = *scalep;
    float4 b4 = *(const float4*)(bias + ((j & 4095) << 2));
    float4 o;
    o.x = fmaf(sc, p0.x + p1.x + p2.x + p3.x, b4.x);
    o.y = fmaf(sc, p0.y + p1.y + p2.y + p3.y, b4.y);
    o.z = fmaf(sc, p0.z + p1.z + p2.z + p3.z, b4.z);
    o.w = fmaf(sc, p0.w + p1.w + p2.w + p3.w, b4.w);
    ((float4*)out)[j] = o;
}

extern "C" void kernel_launch(void* const* d_in, const int* in_sizes, int n_in,
                              void* d_out, int out_size, void* d_ws, size_t ws_size,
                              hipStream_t stream) {
    const float* x      = (const float*)d_in[0];
    const int*   wq     = (const int*)d_in[1];
    const int*   zerop  = (const int*)d_in[2];
    const float* scalep = (const float*)d_in[3];
    const float* bias   = (const float*)d_in[4];
    float*       out    = (float*)d_out;
    float*       part   = (float*)d_ws;     // 4 x 32 x 16384 f32 = 8 MB scratch

    qgemm_part_kernel<<<4096, 256, 0, stream>>>(x, wq, zerop, part);
    reduce_kernel<<<512, 256, 0, stream>>>(part, scalep, bias, out);
}